// Round 4
// baseline (268.655 us; speedup 1.0000x reference)
//
#include <hip/hip_runtime.h>

namespace {
constexpr int N_NODES = 100000;
constexpr int N_EDGES = 640000;
constexpr int SCAN_B = 1024;
constexpr int NSCANB = (N_NODES + SCAN_B - 1) / SCAN_B;  // 98
}

// ---------------- CSR build ----------------

__global__ void k_zero_i32(int* __restrict__ p, int n) {
  int i = blockIdx.x * 256 + threadIdx.x;
  if (i < n) p[i] = 0;
}

__global__ void k_hist(const int* __restrict__ col, int* __restrict__ deg) {
  int i = blockIdx.x * 256 + threadIdx.x;
  if (i < N_EDGES) atomicAdd(&deg[col[i]], 1);
}

__global__ __launch_bounds__(256) void k_scan1(const int* __restrict__ deg,
                                               int* __restrict__ excl,
                                               int* __restrict__ bsum) {
  __shared__ int tmp[256];
  int t = threadIdx.x;
  int base = blockIdx.x * SCAN_B + t * 4;
  int v[4];
#pragma unroll
  for (int j = 0; j < 4; ++j) {
    int g = base + j;
    v[j] = (g < N_NODES) ? deg[g] : 0;
  }
  int s = v[0] + v[1] + v[2] + v[3];
  tmp[t] = s;
  __syncthreads();
  for (int d = 1; d < 256; d <<= 1) {
    int add = (t >= d) ? tmp[t - d] : 0;
    __syncthreads();
    tmp[t] += add;
    __syncthreads();
  }
  int off = tmp[t] - s;
#pragma unroll
  for (int j = 0; j < 4; ++j) {
    int g = base + j;
    if (g < N_NODES) excl[g] = off;
    off += v[j];
  }
  if (t == 255) bsum[blockIdx.x] = tmp[255];
}

__global__ __launch_bounds__(128) void k_scan2(int* __restrict__ bsum) {
  __shared__ int tmp[128];
  int t = threadIdx.x;
  int v = (t < NSCANB) ? bsum[t] : 0;
  tmp[t] = v;
  __syncthreads();
  for (int d = 1; d < 128; d <<= 1) {
    int add = (t >= d) ? tmp[t - d] : 0;
    __syncthreads();
    tmp[t] += add;
    __syncthreads();
  }
  if (t < NSCANB) bsum[t] = tmp[t] - v;  // exclusive
}

__global__ void k_scan3(const int* __restrict__ excl, const int* __restrict__ bsum,
                        const int* __restrict__ deg, int* __restrict__ cursor,
                        float* __restrict__ dinv) {
  int i = blockIdx.x * 256 + threadIdx.x;
  if (i < N_NODES) {
    cursor[i] = excl[i] + bsum[i / SCAN_B];
    dinv[i] = rsqrtf((float)deg[i] + 1.0f);
  }
}

__global__ void k_fill(const int* __restrict__ row, const int* __restrict__ col,
                       int* __restrict__ cursor, int* __restrict__ csr_src) {
  int e = blockIdx.x * 256 + threadIdx.x;
  if (e < N_EDGES) {
    int pos = atomicAdd(&cursor[col[e]], 1);
    csr_src[pos] = row[e];
  }
}
// after k_fill: cursor[n] = end of n's range; start = cursor[n] - deg[n]

// ---------------- GEMM: hs[n,:] = dinv[n] * (relu?(X[n,:]) @ W) ----------------
// 64x64 tile per block, one chunk per block, K split into 2 stages of 64.
// LDS = 16 + 17.4 KB -> 4 blocks/CU (16 waves). Stage-1 loads prefetched
// under stage-0 compute (T14). 4x4 register blocking, all-b128 LDS reads.

template <bool RELU_IN>
__global__ __launch_bounds__(256, 4) void k_gemm(const float* __restrict__ X,
                                                 const float* __restrict__ W,
                                                 const float* __restrict__ dinv,
                                                 float* __restrict__ Y,
                                                 int n_rows, int kout) {
  constexpr int K = 128;
  constexpr int BM = 64;
  constexpr int BN = 64;
  constexpr int KS = 64;      // k per stage
  constexpr int XS = KS + 4;  // 68 floats: 16B-aligned rows, conflict-free
  __shared__ float Wl[KS][BN];   // 16 KB
  __shared__ float Xl[BM][XS];   // 17.4 KB

  const int tid = threadIdx.x;
  const int tx = tid & 15;
  const int ty = tid >> 4;
  const int col0 = blockIdx.y * BN;
  const int base = blockIdx.x * BM;

  // stage 0 global loads -> regs
  float4 px[4], pw[4];
#pragma unroll
  for (int i = 0; i < 4; ++i) {
    int f = tid + i * 256;
    int r = f >> 4, q = f & 15;
    int gr = min(base + r, n_rows - 1);
    px[i] = *(const float4*)&X[(long long)gr * K + q * 4];
    pw[i] = *(const float4*)&W[r * kout + col0 + q * 4];
  }

  float4 acc[4] = {{0, 0, 0, 0}, {0, 0, 0, 0}, {0, 0, 0, 0}, {0, 0, 0, 0}};

#pragma unroll
  for (int s = 0; s < 2; ++s) {
    // regs -> LDS
#pragma unroll
    for (int i = 0; i < 4; ++i) {
      int f = tid + i * 256;
      int r = f >> 4, q = f & 15;
      float4 v = px[i];
      if (RELU_IN) {
        v.x = fmaxf(v.x, 0.f); v.y = fmaxf(v.y, 0.f);
        v.z = fmaxf(v.z, 0.f); v.w = fmaxf(v.w, 0.f);
      }
      *(float4*)&Xl[r][q * 4] = v;
      *(float4*)&Wl[r][q * 4] = pw[i];
    }
    __syncthreads();

    if (s == 0) {
      // prefetch stage 1; completes under stage-0 compute
#pragma unroll
      for (int i = 0; i < 4; ++i) {
        int f = tid + i * 256;
        int r = f >> 4, q = f & 15;
        int gr = min(base + r, n_rows - 1);
        px[i] = *(const float4*)&X[(long long)gr * K + KS + q * 4];
        pw[i] = *(const float4*)&W[(KS + r) * kout + col0 + q * 4];
      }
    }

#pragma unroll 8
    for (int k0 = 0; k0 < KS; k0 += 4) {
      float4 wq[4], xr[4];
#pragma unroll
      for (int j = 0; j < 4; ++j) wq[j] = *(float4*)&Wl[k0 + j][tx * 4];
#pragma unroll
      for (int r = 0; r < 4; ++r) xr[r] = *(float4*)&Xl[ty * 4 + r][k0];
#pragma unroll
      for (int r = 0; r < 4; ++r) {
        acc[r].x += xr[r].x * wq[0].x; acc[r].y += xr[r].x * wq[0].y;
        acc[r].z += xr[r].x * wq[0].z; acc[r].w += xr[r].x * wq[0].w;
        acc[r].x += xr[r].y * wq[1].x; acc[r].y += xr[r].y * wq[1].y;
        acc[r].z += xr[r].y * wq[1].z; acc[r].w += xr[r].y * wq[1].w;
        acc[r].x += xr[r].z * wq[2].x; acc[r].y += xr[r].z * wq[2].y;
        acc[r].z += xr[r].z * wq[2].z; acc[r].w += xr[r].z * wq[2].w;
        acc[r].x += xr[r].w * wq[3].x; acc[r].y += xr[r].w * wq[3].y;
        acc[r].z += xr[r].w * wq[3].z; acc[r].w += xr[r].w * wq[3].w;
      }
    }
    if (s == 0) __syncthreads();  // all reads of stage-0 LDS done before overwrite
  }

#pragma unroll
  for (int r = 0; r < 4; ++r) {
    int row = base + ty * 4 + r;
    if (row < n_rows) {
      float sc = dinv[row];
      float4 o = {acc[r].x * sc, acc[r].y * sc, acc[r].z * sc, acc[r].w * sc};
      *(float4*)&Y[(long long)row * kout + col0 + tx * 4] = o;
    }
  }
}

// ---------- gather: out[n] = bias + dinv[n] * (hs[n] + sum_{src in CSR(n)} hs[src]) ----------

template <int C>
__global__ __launch_bounds__(256) void k_gather(const int* __restrict__ cursor,
                                                const int* __restrict__ deg,
                                                const int* __restrict__ csr_src,
                                                const float* __restrict__ dinv,
                                                const float* __restrict__ hs,
                                                const float* __restrict__ bias,
                                                float* __restrict__ out) {
  constexpr int Q = C / 4;
  int idx = blockIdx.x * 256 + threadIdx.x;
  if (idx >= N_NODES * Q) return;
  int n = idx / Q, q = idx % Q;
  float d = dinv[n];
  int end = cursor[n];
  int dg = deg[n];
  float4 bv = *(const float4*)&bias[q * 4];
  float4 acc = *(const float4*)&hs[(long long)n * C + q * 4];  // self-loop
  int s = end - dg;
  // unroll-2 for a little ILP on the src->hs dependent chain
  for (; s + 2 <= end; s += 2) {
    int s0 = csr_src[s], s1 = csr_src[s + 1];
    float4 v0 = *(const float4*)&hs[(long long)s0 * C + q * 4];
    float4 v1 = *(const float4*)&hs[(long long)s1 * C + q * 4];
    acc.x += v0.x + v1.x; acc.y += v0.y + v1.y;
    acc.z += v0.z + v1.z; acc.w += v0.w + v1.w;
  }
  if (s < end) {
    int s0 = csr_src[s];
    float4 v0 = *(const float4*)&hs[(long long)s0 * C + q * 4];
    acc.x += v0.x; acc.y += v0.y; acc.z += v0.z; acc.w += v0.w;
  }
  float4 o = {bv.x + d * acc.x, bv.y + d * acc.y, bv.z + d * acc.z, bv.w + d * acc.w};
  *(float4*)&out[(long long)n * C + q * 4] = o;
}

// ---------------- launch ----------------

extern "C" void kernel_launch(void* const* d_in, const int* in_sizes, int n_in,
                              void* d_out, int out_size, void* d_ws, size_t ws_size,
                              hipStream_t stream) {
  const float* x = (const float*)d_in[0];
  const int* ei = (const int*)d_in[1];
  const int* erow = ei;            // sources
  const int* ecol = ei + N_EDGES;  // targets
  const float* W1 = (const float*)d_in[2];
  const float* b1 = (const float*)d_in[3];
  const float* W2 = (const float*)d_in[4];
  const float* b2 = (const float*)d_in[5];
  float* out = (float*)d_out;

  char* ws = (char*)d_ws;
  int* deg = (int*)(ws + 0);
  int* cursor = (int*)(ws + 400128);
  int* excl = (int*)(ws + 800256);
  int* bsum = (int*)(ws + 1200384);
  int* csr_src = (int*)(ws + 1200896);
  float* dinv = (float*)(ws + 3760896);
  float* hs1 = (float*)(ws + 4161024);
  float* agg1 = (float*)(ws + 55361024);
  float* hs2 = hs1;  // hs1 dead after gather1

  // CSR build
  k_zero_i32<<<(N_NODES + 255) / 256, 256, 0, stream>>>(deg, N_NODES);
  k_hist<<<(N_EDGES + 255) / 256, 256, 0, stream>>>(ecol, deg);
  k_scan1<<<NSCANB, 256, 0, stream>>>(deg, excl, bsum);
  k_scan2<<<1, 128, 0, stream>>>(bsum);
  k_scan3<<<(N_NODES + 255) / 256, 256, 0, stream>>>(excl, bsum, deg, cursor, dinv);
  k_fill<<<(N_EDGES + 255) / 256, 256, 0, stream>>>(erow, ecol, cursor, csr_src);

  const int nchunks = (N_NODES + 63) / 64;  // 1563

  // layer 1
  dim3 g1(nchunks, 2);
  k_gemm<false><<<g1, 256, 0, stream>>>(x, W1, dinv, hs1, N_NODES, 128);
  k_gather<128><<<(N_NODES * 32 + 255) / 256, 256, 0, stream>>>(cursor, deg, csr_src, dinv,
                                                                hs1, b1, agg1);

  // layer 2
  dim3 g2(nchunks, 1);
  k_gemm<true><<<g2, 256, 0, stream>>>(agg1, W2, dinv, hs2, N_NODES, 64);
  k_gather<64><<<(N_NODES * 16 + 255) / 256, 256, 0, stream>>>(cursor, deg, csr_src, dinv,
                                                               hs2, b2, out);
}

// Round 5
// 203.650 us; speedup vs baseline: 1.3192x; 1.3192x over previous
//
#include <hip/hip_runtime.h>

namespace {
constexpr int N_NODES = 100000;
constexpr int N_EDGES = 640000;
constexpr int SCAN_B = 1024;
constexpr int NSCANB = (N_NODES + SCAN_B - 1) / SCAN_B;  // 98
constexpr int ROWTILES = N_NODES / 16;                   // 6250 (exact)
}

typedef short bf16x8 __attribute__((ext_vector_type(8)));
typedef float f32x4 __attribute__((ext_vector_type(4)));

static __device__ inline uint32_t cvt_pk_bf16(float a, float b) {
  uint32_t r;
  asm volatile("v_cvt_pk_bf16_f32 %0, %1, %2" : "=v"(r) : "v"(a), "v"(b));
  return r;  // lo = bf16(a), hi = bf16(b) — order irrelevant: same packing used for A and B
}

// ---------------- CSR build ----------------

__global__ void k_zero_i32(int* __restrict__ p, int n) {
  int i = blockIdx.x * 256 + threadIdx.x;
  if (i < n) p[i] = 0;
}

__global__ void k_hist(const int* __restrict__ col, int* __restrict__ deg) {
  int i = blockIdx.x * 256 + threadIdx.x;
  if (i < N_EDGES) atomicAdd(&deg[col[i]], 1);
}

__global__ __launch_bounds__(256) void k_scan1(const int* __restrict__ deg,
                                               int* __restrict__ excl,
                                               int* __restrict__ bsum) {
  __shared__ int tmp[256];
  int t = threadIdx.x;
  int base = blockIdx.x * SCAN_B + t * 4;
  int v[4];
#pragma unroll
  for (int j = 0; j < 4; ++j) {
    int g = base + j;
    v[j] = (g < N_NODES) ? deg[g] : 0;
  }
  int s = v[0] + v[1] + v[2] + v[3];
  tmp[t] = s;
  __syncthreads();
  for (int d = 1; d < 256; d <<= 1) {
    int add = (t >= d) ? tmp[t - d] : 0;
    __syncthreads();
    tmp[t] += add;
    __syncthreads();
  }
  int off = tmp[t] - s;
#pragma unroll
  for (int j = 0; j < 4; ++j) {
    int g = base + j;
    if (g < N_NODES) excl[g] = off;
    off += v[j];
  }
  if (t == 255) bsum[blockIdx.x] = tmp[255];
}

__global__ __launch_bounds__(128) void k_scan2(int* __restrict__ bsum) {
  __shared__ int tmp[128];
  int t = threadIdx.x;
  int v = (t < NSCANB) ? bsum[t] : 0;
  tmp[t] = v;
  __syncthreads();
  for (int d = 1; d < 128; d <<= 1) {
    int add = (t >= d) ? tmp[t - d] : 0;
    __syncthreads();
    tmp[t] += add;
    __syncthreads();
  }
  if (t < NSCANB) bsum[t] = tmp[t] - v;  // exclusive
}

__global__ void k_scan3(const int* __restrict__ excl, const int* __restrict__ bsum,
                        const int* __restrict__ deg, int* __restrict__ cursor,
                        float* __restrict__ dinv) {
  int i = blockIdx.x * 256 + threadIdx.x;
  if (i < N_NODES) {
    cursor[i] = excl[i] + bsum[i / SCAN_B];
    dinv[i] = rsqrtf((float)deg[i] + 1.0f);
  }
}

__global__ void k_fill(const int* __restrict__ row, const int* __restrict__ col,
                       int* __restrict__ cursor, int* __restrict__ csr_src) {
  int e = blockIdx.x * 256 + threadIdx.x;
  if (e < N_EDGES) {
    int pos = atomicAdd(&cursor[col[e]], 1);
    csr_src[pos] = row[e];
  }
}
// after k_fill: cursor[n] = end of n's range; start = cursor[n] - deg[n]

// ---------------- W prep: pack W[128 x KOUT] into per-lane bf16 MFMA B-fragments ----
// frag (ks, nt): lane l holds W[ks*32 + (l>>4)*8 + j][nt*16 + (l&15)], j=0..7,
// packed u32[p] = cvt_pk(w[2p], w[2p+1]) — IDENTICAL mapping to the A-side packing.

template <int KOUT>
__global__ void k_wprep(const float* __restrict__ W, uint4* __restrict__ wfrag) {
  constexpr int NT = KOUT / 16;
  int idx = blockIdx.x * 256 + threadIdx.x;
  if (idx >= 4 * NT * 64) return;
  int lane = idx & 63;
  int nt = (idx >> 6) % NT;
  int ks = idx / (64 * NT);
  int g = lane >> 4, c = lane & 15;
  const float* wp = W + (ks * 32 + g * 8) * KOUT + nt * 16 + c;
  float w[8];
#pragma unroll
  for (int j = 0; j < 8; ++j) w[j] = wp[j * KOUT];
  uint4 o;
  o.x = cvt_pk_bf16(w[0], w[1]);
  o.y = cvt_pk_bf16(w[2], w[3]);
  o.z = cvt_pk_bf16(w[4], w[5]);
  o.w = cvt_pk_bf16(w[6], w[7]);
  wfrag[idx] = o;
}

// ---------------- MFMA GEMM: hs[n,:] = dinv[n] * (relu?(X[n,:]) @ W) ----------------
// One wave per 16-row stripe x full KOUT. No LDS, no barriers. A-frags loaded
// straight from global (coalesced 128B/row per k-step) + cvt_pk; B-frags from wfrag.

template <int KOUT, bool RELU_IN>
__global__ __launch_bounds__(256) void k_gemm_mfma(const float* __restrict__ X,
                                                   const uint4* __restrict__ wfrag,
                                                   const float* __restrict__ dinv,
                                                   float* __restrict__ Y) {
  constexpr int NT = KOUT / 16;
  const int tid = threadIdx.x;
  const int w = blockIdx.x * 4 + (tid >> 6);
  if (w >= ROWTILES) return;
  const int lane = tid & 63;
  const int g = lane >> 4, c = lane & 15;
  const int rb = w * 16;

  f32x4 acc[NT];
#pragma unroll
  for (int nt = 0; nt < NT; ++nt) acc[nt] = (f32x4){0.f, 0.f, 0.f, 0.f};

  const float* xrow = X + (long long)(rb + c) * 128 + g * 8;
  const bf16x8* wf = (const bf16x8*)wfrag;

#pragma unroll
  for (int ks = 0; ks < 4; ++ks) {
    float4 a0 = *(const float4*)(xrow + ks * 32);
    float4 a1 = *(const float4*)(xrow + ks * 32 + 4);
    if (RELU_IN) {
      a0.x = fmaxf(a0.x, 0.f); a0.y = fmaxf(a0.y, 0.f);
      a0.z = fmaxf(a0.z, 0.f); a0.w = fmaxf(a0.w, 0.f);
      a1.x = fmaxf(a1.x, 0.f); a1.y = fmaxf(a1.y, 0.f);
      a1.z = fmaxf(a1.z, 0.f); a1.w = fmaxf(a1.w, 0.f);
    }
    union { bf16x8 v; uint32_t u[4]; } af;
    af.u[0] = cvt_pk_bf16(a0.x, a0.y);
    af.u[1] = cvt_pk_bf16(a0.z, a0.w);
    af.u[2] = cvt_pk_bf16(a1.x, a1.y);
    af.u[3] = cvt_pk_bf16(a1.z, a1.w);
#pragma unroll
    for (int nt = 0; nt < NT; ++nt) {
      bf16x8 bf = wf[(ks * NT + nt) * 64 + lane];
      acc[nt] = __builtin_amdgcn_mfma_f32_16x16x32_bf16(af.v, bf, acc[nt], 0, 0, 0);
    }
  }

  // C/D layout (m89-verified): col = lane&15, row = (lane>>4)*4 + reg
#pragma unroll
  for (int r = 0; r < 4; ++r) {
    int row = rb + g * 4 + r;
    float s = dinv[row];
#pragma unroll
    for (int nt = 0; nt < NT; ++nt) {
      Y[(long long)row * KOUT + nt * 16 + c] = acc[nt][r] * s;
    }
  }
}

// ---------- gather: out[n] = bias + dinv[n] * (hs[n] + sum_{src in CSR(n)} hs[src]) ----------

template <int C>
__global__ __launch_bounds__(256) void k_gather(const int* __restrict__ cursor,
                                                const int* __restrict__ deg,
                                                const int* __restrict__ csr_src,
                                                const float* __restrict__ dinv,
                                                const float* __restrict__ hs,
                                                const float* __restrict__ bias,
                                                float* __restrict__ out) {
  constexpr int Q = C / 4;
  int idx = blockIdx.x * 256 + threadIdx.x;
  if (idx >= N_NODES * Q) return;
  int n = idx / Q, q = idx % Q;
  float d = dinv[n];
  int end = cursor[n];
  int dg = deg[n];
  float4 bv = *(const float4*)&bias[q * 4];
  float4 acc = *(const float4*)&hs[(long long)n * C + q * 4];  // self-loop
  int s = end - dg;
  for (; s + 2 <= end; s += 2) {
    int s0 = csr_src[s], s1 = csr_src[s + 1];
    float4 v0 = *(const float4*)&hs[(long long)s0 * C + q * 4];
    float4 v1 = *(const float4*)&hs[(long long)s1 * C + q * 4];
    acc.x += v0.x + v1.x; acc.y += v0.y + v1.y;
    acc.z += v0.z + v1.z; acc.w += v0.w + v1.w;
  }
  if (s < end) {
    int s0 = csr_src[s];
    float4 v0 = *(const float4*)&hs[(long long)s0 * C + q * 4];
    acc.x += v0.x; acc.y += v0.y; acc.z += v0.z; acc.w += v0.w;
  }
  float4 o = {bv.x + d * acc.x, bv.y + d * acc.y, bv.z + d * acc.z, bv.w + d * acc.w};
  *(float4*)&out[(long long)n * C + q * 4] = o;
}

// ---------------- launch ----------------

extern "C" void kernel_launch(void* const* d_in, const int* in_sizes, int n_in,
                              void* d_out, int out_size, void* d_ws, size_t ws_size,
                              hipStream_t stream) {
  const float* x = (const float*)d_in[0];
  const int* ei = (const int*)d_in[1];
  const int* erow = ei;            // sources
  const int* ecol = ei + N_EDGES;  // targets
  const float* W1 = (const float*)d_in[2];
  const float* b1 = (const float*)d_in[3];
  const float* W2 = (const float*)d_in[4];
  const float* b2 = (const float*)d_in[5];
  float* out = (float*)d_out;

  char* ws = (char*)d_ws;
  int* deg = (int*)(ws + 0);
  int* cursor = (int*)(ws + 400128);
  int* excl = (int*)(ws + 800256);
  int* bsum = (int*)(ws + 1200384);
  int* csr_src = (int*)(ws + 1200896);
  float* dinv = (float*)(ws + 3760896);
  float* hs1 = (float*)(ws + 4161024);
  float* agg1 = (float*)(ws + 55361024);
  float* hs2 = hs1;  // hs1 dead after gather1
  uint4* wfrag1 = (uint4*)(ws + 106561024);  // 4*8*64*16 = 32 KB
  uint4* wfrag2 = (uint4*)(ws + 106593792);  // 4*4*64*16 = 16 KB

  // W fragment prep (independent of CSR)
  k_wprep<128><<<(4 * 8 * 64 + 255) / 256, 256, 0, stream>>>(W1, wfrag1);
  k_wprep<64><<<(4 * 4 * 64 + 255) / 256, 256, 0, stream>>>(W2, wfrag2);

  // CSR build
  k_zero_i32<<<(N_NODES + 255) / 256, 256, 0, stream>>>(deg, N_NODES);
  k_hist<<<(N_EDGES + 255) / 256, 256, 0, stream>>>(ecol, deg);
  k_scan1<<<NSCANB, 256, 0, stream>>>(deg, excl, bsum);
  k_scan2<<<1, 128, 0, stream>>>(bsum);
  k_scan3<<<(N_NODES + 255) / 256, 256, 0, stream>>>(excl, bsum, deg, cursor, dinv);
  k_fill<<<(N_EDGES + 255) / 256, 256, 0, stream>>>(erow, ecol, cursor, csr_src);

  const int gblocks = (ROWTILES + 3) / 4;  // 1563

  // layer 1
  k_gemm_mfma<128, false><<<gblocks, 256, 0, stream>>>(x, wfrag1, dinv, hs1);
  k_gather<128><<<(N_NODES * 32 + 255) / 256, 256, 0, stream>>>(cursor, deg, csr_src, dinv,
                                                                hs1, b1, agg1);

  // layer 2
  k_gemm_mfma<64, true><<<gblocks, 256, 0, stream>>>(agg1, wfrag2, dinv, hs2);
  k_gather<64><<<(N_NODES * 16 + 255) / 256, 256, 0, stream>>>(cursor, deg, csr_src, dinv,
                                                               hs2, b2, out);
}

// Round 6
// 164.521 us; speedup vs baseline: 1.6330x; 1.2378x over previous
//
#include <hip/hip_runtime.h>

namespace {
constexpr int N_NODES = 100000;
constexpr int N_EDGES = 640000;
constexpr int SCAN_B = 1024;
constexpr int NSCANB = (N_NODES + SCAN_B - 1) / SCAN_B;  // 98
constexpr int ROWTILES = N_NODES / 16;                   // 6250 (exact)
}

typedef short bf16x8 __attribute__((ext_vector_type(8)));
typedef float f32x4 __attribute__((ext_vector_type(4)));

static __device__ inline uint32_t cvt_pk_bf16(float a, float b) {
  uint32_t r;
  asm volatile("v_cvt_pk_bf16_f32 %0, %1, %2" : "=v"(r) : "v"(a), "v"(b));
  return r;  // lo = bf16(a) RNE, hi = bf16(b)
}

// 8 bf16 (uint4) -> 8 f32
static __device__ inline void bf8_to_f32(uint4 u, float* v) {
  v[0] = __uint_as_float(u.x << 16);
  v[1] = __uint_as_float(u.x & 0xffff0000u);
  v[2] = __uint_as_float(u.y << 16);
  v[3] = __uint_as_float(u.y & 0xffff0000u);
  v[4] = __uint_as_float(u.z << 16);
  v[5] = __uint_as_float(u.z & 0xffff0000u);
  v[6] = __uint_as_float(u.w << 16);
  v[7] = __uint_as_float(u.w & 0xffff0000u);
}

static __device__ inline uint4 f32_to_bf8(const float* v) {
  uint4 o;
  o.x = cvt_pk_bf16(v[0], v[1]);
  o.y = cvt_pk_bf16(v[2], v[3]);
  o.z = cvt_pk_bf16(v[4], v[5]);
  o.w = cvt_pk_bf16(v[6], v[7]);
  return o;
}

// ---------------- CSR build ----------------

__global__ void k_zero_i32(int* __restrict__ p, int n) {
  int i = blockIdx.x * 256 + threadIdx.x;
  if (i < n) p[i] = 0;
}

__global__ void k_hist(const int* __restrict__ col, int* __restrict__ deg) {
  int i = blockIdx.x * 256 + threadIdx.x;
  if (i < N_EDGES) atomicAdd(&deg[col[i]], 1);
}

__global__ __launch_bounds__(256) void k_scan1(const int* __restrict__ deg,
                                               int* __restrict__ excl,
                                               int* __restrict__ bsum) {
  __shared__ int tmp[256];
  int t = threadIdx.x;
  int base = blockIdx.x * SCAN_B + t * 4;
  int v[4];
#pragma unroll
  for (int j = 0; j < 4; ++j) {
    int g = base + j;
    v[j] = (g < N_NODES) ? deg[g] : 0;
  }
  int s = v[0] + v[1] + v[2] + v[3];
  tmp[t] = s;
  __syncthreads();
  for (int d = 1; d < 256; d <<= 1) {
    int add = (t >= d) ? tmp[t - d] : 0;
    __syncthreads();
    tmp[t] += add;
    __syncthreads();
  }
  int off = tmp[t] - s;
#pragma unroll
  for (int j = 0; j < 4; ++j) {
    int g = base + j;
    if (g < N_NODES) excl[g] = off;
    off += v[j];
  }
  if (t == 255) bsum[blockIdx.x] = tmp[255];
}

__global__ __launch_bounds__(128) void k_scan2(int* __restrict__ bsum) {
  __shared__ int tmp[128];
  int t = threadIdx.x;
  int v = (t < NSCANB) ? bsum[t] : 0;
  tmp[t] = v;
  __syncthreads();
  for (int d = 1; d < 128; d <<= 1) {
    int add = (t >= d) ? tmp[t - d] : 0;
    __syncthreads();
    tmp[t] += add;
    __syncthreads();
  }
  if (t < NSCANB) bsum[t] = tmp[t] - v;  // exclusive
}

__global__ void k_scan3(const int* __restrict__ excl, const int* __restrict__ bsum,
                        const int* __restrict__ deg, int* __restrict__ cursor,
                        float* __restrict__ dinv) {
  int i = blockIdx.x * 256 + threadIdx.x;
  if (i < N_NODES) {
    cursor[i] = excl[i] + bsum[i / SCAN_B];
    dinv[i] = rsqrtf((float)deg[i] + 1.0f);
  }
}

__global__ void k_fill(const int* __restrict__ row, const int* __restrict__ col,
                       int* __restrict__ cursor, int* __restrict__ csr_src) {
  int e = blockIdx.x * 256 + threadIdx.x;
  if (e < N_EDGES) {
    int pos = atomicAdd(&cursor[col[e]], 1);
    csr_src[pos] = row[e];
  }
}
// after k_fill: cursor[n] = end of n's range; start = cursor[n] - deg[n]

// ---------------- W prep: per-lane bf16 MFMA B-fragments ----------------
// frag (ks, nt): lane l holds W[ks*32 + (l>>4)*8 + j][nt*16 + (l&15)], j=0..7,
// u32[p] = cvt_pk(w[2p], w[2p+1]) — identical (lane, elem)->k map as the A side.

template <int KOUT>
__global__ void k_wprep(const float* __restrict__ W, uint4* __restrict__ wfrag) {
  constexpr int NT = KOUT / 16;
  int idx = blockIdx.x * 256 + threadIdx.x;
  if (idx >= 4 * NT * 64) return;
  int lane = idx & 63;
  int nt = (idx >> 6) % NT;
  int ks = idx / (64 * NT);
  int g = lane >> 4, c = lane & 15;
  const float* wp = W + (ks * 32 + g * 8) * KOUT + nt * 16 + c;
  float w[8];
#pragma unroll
  for (int j = 0; j < 8; ++j) w[j] = wp[j * KOUT];
  wfrag[idx] = f32_to_bf8(w);
}

// ---------------- MFMA GEMM: hs[n,:] = bf16( dinv[n] * (X[n,:] @ W) ) ------------
// One wave per 16-row stripe x full KOUT. No LDS, no barriers.
// A_BF16: X is bf16 (direct bf16x8 loads); else f32 + cvt_pk.

template <int KOUT, bool A_BF16>
__global__ __launch_bounds__(256) void k_gemm_mfma(const void* __restrict__ Xv,
                                                   const uint4* __restrict__ wfrag,
                                                   const float* __restrict__ dinv,
                                                   unsigned short* __restrict__ Yb) {
  constexpr int NT = KOUT / 16;
  const int tid = threadIdx.x;
  const int w = blockIdx.x * 4 + (tid >> 6);
  if (w >= ROWTILES) return;
  const int lane = tid & 63;
  const int g = lane >> 4, c = lane & 15;
  const int rb = w * 16;

  f32x4 acc[NT];
#pragma unroll
  for (int nt = 0; nt < NT; ++nt) acc[nt] = (f32x4){0.f, 0.f, 0.f, 0.f};

  const bf16x8* wf = (const bf16x8*)wfrag;

#pragma unroll
  for (int ks = 0; ks < 4; ++ks) {
    bf16x8 av;
    if (A_BF16) {
      const unsigned short* xrow =
          (const unsigned short*)Xv + (long long)(rb + c) * 128 + g * 8;
      av = *(const bf16x8*)(xrow + ks * 32);
    } else {
      const float* xrow = (const float*)Xv + (long long)(rb + c) * 128 + g * 8;
      float4 a0 = *(const float4*)(xrow + ks * 32);
      float4 a1 = *(const float4*)(xrow + ks * 32 + 4);
      union { bf16x8 v; uint32_t u[4]; } af;
      af.u[0] = cvt_pk_bf16(a0.x, a0.y);
      af.u[1] = cvt_pk_bf16(a0.z, a0.w);
      af.u[2] = cvt_pk_bf16(a1.x, a1.y);
      af.u[3] = cvt_pk_bf16(a1.z, a1.w);
      av = af.v;
    }
#pragma unroll
    for (int nt = 0; nt < NT; ++nt) {
      bf16x8 bf = wf[(ks * NT + nt) * 64 + lane];
      acc[nt] = __builtin_amdgcn_mfma_f32_16x16x32_bf16(av, bf, acc[nt], 0, 0, 0);
    }
  }

  // C/D layout (m89-verified): col = lane&15, row = (lane>>4)*4 + reg
#pragma unroll
  for (int r = 0; r < 4; ++r) {
    int row = rb + g * 4 + r;
    float s = dinv[row];
#pragma unroll
    for (int nt = 0; nt < NT; ++nt) {
      float val = acc[nt][r] * s;
      Yb[(long long)row * KOUT + nt * 16 + c] = (unsigned short)cvt_pk_bf16(val, val);
    }
  }
}

// ---- gather: res[n] = bias + dinv[n]*(hs[n] + sum_src hs[src]); bf16 in, bf16/f32 out ----

template <int C, bool RELU_OUT, bool OUT_BF16>
__global__ __launch_bounds__(256) void k_gather(const int* __restrict__ cursor,
                                                const int* __restrict__ deg,
                                                const int* __restrict__ csr_src,
                                                const float* __restrict__ dinv,
                                                const unsigned short* __restrict__ hs,
                                                const float* __restrict__ bias,
                                                void* __restrict__ outv) {
  constexpr int Q = C / 8;  // threads per node
  int idx = blockIdx.x * 256 + threadIdx.x;
  if (idx >= N_NODES * Q) return;
  int n = idx / Q, q = idx % Q;
  float d = dinv[n];
  int end = cursor[n];
  int dg = deg[n];

  float acc[8];
  bf8_to_f32(*(const uint4*)&hs[(long long)n * C + q * 8], acc);  // self term

  int s = end - dg;
  for (; s + 2 <= end; s += 2) {
    int s0 = csr_src[s], s1 = csr_src[s + 1];
    uint4 u0 = *(const uint4*)&hs[(long long)s0 * C + q * 8];
    uint4 u1 = *(const uint4*)&hs[(long long)s1 * C + q * 8];
    float v0[8], v1[8];
    bf8_to_f32(u0, v0);
    bf8_to_f32(u1, v1);
#pragma unroll
    for (int j = 0; j < 8; ++j) acc[j] += v0[j] + v1[j];
  }
  if (s < end) {
    int s0 = csr_src[s];
    float v0[8];
    bf8_to_f32(*(const uint4*)&hs[(long long)s0 * C + q * 8], v0);
#pragma unroll
    for (int j = 0; j < 8; ++j) acc[j] += v0[j];
  }

  float res[8];
#pragma unroll
  for (int j = 0; j < 8; ++j) {
    res[j] = bias[q * 8 + j] + d * acc[j];
    if (RELU_OUT) res[j] = fmaxf(res[j], 0.f);
  }

  if (OUT_BF16) {
    unsigned short* out = (unsigned short*)outv;
    *(uint4*)&out[(long long)n * C + q * 8] = f32_to_bf8(res);
  } else {
    float* out = (float*)outv;
    *(float4*)&out[(long long)n * C + q * 8] = *(float4*)&res[0];
    *(float4*)&out[(long long)n * C + q * 8 + 4] = *(float4*)&res[4];
  }
}

// ---------------- launch ----------------

extern "C" void kernel_launch(void* const* d_in, const int* in_sizes, int n_in,
                              void* d_out, int out_size, void* d_ws, size_t ws_size,
                              hipStream_t stream) {
  const float* x = (const float*)d_in[0];
  const int* ei = (const int*)d_in[1];
  const int* erow = ei;            // sources
  const int* ecol = ei + N_EDGES;  // targets
  const float* W1 = (const float*)d_in[2];
  const float* b1 = (const float*)d_in[3];
  const float* W2 = (const float*)d_in[4];
  const float* b2 = (const float*)d_in[5];
  float* out = (float*)d_out;

  char* ws = (char*)d_ws;
  int* deg = (int*)(ws + 0);                       // 400,000 B
  int* cursor = (int*)(ws + 400128);               // 400,000 B
  int* excl = (int*)(ws + 800256);                 // 400,000 B
  int* bsum = (int*)(ws + 1200384);                // 512 B
  int* csr_src = (int*)(ws + 1200896);             // 2,560,000 B
  float* dinv = (float*)(ws + 3760896);            // 400,000 B
  unsigned short* hs1 = (unsigned short*)(ws + 4161024);    // 25.6 MB (bf16)
  unsigned short* agg1 = (unsigned short*)(ws + 29761024);  // 25.6 MB (bf16)
  unsigned short* hs2 = (unsigned short*)(ws + 55361024);   // 12.8 MB (bf16)
  uint4* wfrag1 = (uint4*)(ws + 68161024);         // 32 KB
  uint4* wfrag2 = (uint4*)(ws + 68193792);         // 16 KB

  // W fragment prep (independent of CSR)
  k_wprep<128><<<(4 * 8 * 64 + 255) / 256, 256, 0, stream>>>(W1, wfrag1);
  k_wprep<64><<<(4 * 4 * 64 + 255) / 256, 256, 0, stream>>>(W2, wfrag2);

  // CSR build
  k_zero_i32<<<(N_NODES + 255) / 256, 256, 0, stream>>>(deg, N_NODES);
  k_hist<<<(N_EDGES + 255) / 256, 256, 0, stream>>>(ecol, deg);
  k_scan1<<<NSCANB, 256, 0, stream>>>(deg, excl, bsum);
  k_scan2<<<1, 128, 0, stream>>>(bsum);
  k_scan3<<<(N_NODES + 255) / 256, 256, 0, stream>>>(excl, bsum, deg, cursor, dinv);
  k_fill<<<(N_EDGES + 255) / 256, 256, 0, stream>>>(erow, ecol, cursor, csr_src);

  const int gblocks = (ROWTILES + 3) / 4;  // 1563

  // layer 1: hs1 = bf16(dinv * (x @ W1)); agg1 = bf16(relu(b1 + dinv*(hs1 + gather)))
  k_gemm_mfma<128, false><<<gblocks, 256, 0, stream>>>(x, wfrag1, dinv, hs1);
  k_gather<128, true, true><<<N_NODES * 16 / 256, 256, 0, stream>>>(
      cursor, deg, csr_src, dinv, hs1, b1, agg1);

  // layer 2: hs2 = bf16(dinv * (agg1 @ W2)); out = f32(b2 + dinv*(hs2 + gather))
  k_gemm_mfma<64, true><<<gblocks, 256, 0, stream>>>(agg1, wfrag2, dinv, hs2);
  k_gather<64, false, false><<<N_NODES * 8 / 256, 256, 0, stream>>>(
      cursor, deg, csr_src, dinv, hs2, b2, out);
}

// Round 7
// 161.301 us; speedup vs baseline: 1.6655x; 1.0200x over previous
//
#include <hip/hip_runtime.h>

namespace {
constexpr int N_NODES = 100000;
constexpr int N_EDGES = 640000;
constexpr int SCAN_B = 1024;
constexpr int NSCANB = (N_NODES + SCAN_B - 1) / SCAN_B;  // 98
constexpr int ROWTILES = N_NODES / 16;                   // 6250 (exact)
}

typedef short bf16x8 __attribute__((ext_vector_type(8)));
typedef float f32x4 __attribute__((ext_vector_type(4)));

static __device__ inline uint32_t cvt_pk_bf16(float a, float b) {
  uint32_t r;
  asm volatile("v_cvt_pk_bf16_f32 %0, %1, %2" : "=v"(r) : "v"(a), "v"(b));
  return r;  // lo = bf16(a) RNE, hi = bf16(b)
}

// 8 bf16 (uint4) -> 8 f32
static __device__ inline void bf8_to_f32(uint4 u, float* v) {
  v[0] = __uint_as_float(u.x << 16);
  v[1] = __uint_as_float(u.x & 0xffff0000u);
  v[2] = __uint_as_float(u.y << 16);
  v[3] = __uint_as_float(u.y & 0xffff0000u);
  v[4] = __uint_as_float(u.z << 16);
  v[5] = __uint_as_float(u.z & 0xffff0000u);
  v[6] = __uint_as_float(u.w << 16);
  v[7] = __uint_as_float(u.w & 0xffff0000u);
}

static __device__ inline uint4 f32_to_bf8(const float* v) {
  uint4 o;
  o.x = cvt_pk_bf16(v[0], v[1]);
  o.y = cvt_pk_bf16(v[2], v[3]);
  o.z = cvt_pk_bf16(v[4], v[5]);
  o.w = cvt_pk_bf16(v[6], v[7]);
  return o;
}

// ---------------- CSR build ----------------

__global__ void k_hist(const int* __restrict__ col, int* __restrict__ deg) {
  int i = blockIdx.x * 256 + threadIdx.x;
  if (i < N_EDGES) atomicAdd(&deg[col[i]], 1);
}

__global__ __launch_bounds__(256) void k_scan1(const int* __restrict__ deg,
                                               int* __restrict__ excl,
                                               int* __restrict__ bsum) {
  __shared__ int tmp[256];
  int t = threadIdx.x;
  int base = blockIdx.x * SCAN_B + t * 4;
  int v[4];
#pragma unroll
  for (int j = 0; j < 4; ++j) {
    int g = base + j;
    v[j] = (g < N_NODES) ? deg[g] : 0;
  }
  int s = v[0] + v[1] + v[2] + v[3];
  tmp[t] = s;
  __syncthreads();
  for (int d = 1; d < 256; d <<= 1) {
    int add = (t >= d) ? tmp[t - d] : 0;
    __syncthreads();
    tmp[t] += add;
    __syncthreads();
  }
  int off = tmp[t] - s;
#pragma unroll
  for (int j = 0; j < 4; ++j) {
    int g = base + j;
    if (g < N_NODES) excl[g] = off;
    off += v[j];
  }
  if (t == 255) bsum[blockIdx.x] = tmp[255];
}

__global__ __launch_bounds__(128) void k_scan2(int* __restrict__ bsum) {
  __shared__ int tmp[128];
  int t = threadIdx.x;
  int v = (t < NSCANB) ? bsum[t] : 0;
  tmp[t] = v;
  __syncthreads();
  for (int d = 1; d < 128; d <<= 1) {
    int add = (t >= d) ? tmp[t - d] : 0;
    __syncthreads();
    tmp[t] += add;
    __syncthreads();
  }
  if (t < NSCANB) bsum[t] = tmp[t] - v;  // exclusive
}

__global__ void k_scan3(const int* __restrict__ excl, const int* __restrict__ bsum,
                        const int* __restrict__ deg, int* __restrict__ cursor,
                        float* __restrict__ dinv) {
  int i = blockIdx.x * 256 + threadIdx.x;
  if (i < N_NODES) {
    cursor[i] = excl[i] + bsum[i / SCAN_B];
    dinv[i] = rsqrtf((float)deg[i] + 1.0f);
  }
}

__global__ void k_fill(const int* __restrict__ row, const int* __restrict__ col,
                       int* __restrict__ cursor, int* __restrict__ csr_src) {
  int e = blockIdx.x * 256 + threadIdx.x;
  if (e < N_EDGES) {
    int pos = atomicAdd(&cursor[col[e]], 1);
    csr_src[pos] = row[e];
  }
}
// after k_fill: cursor[n] = end of n's range; start = cursor[n] - deg[n]

// ---------------- W prep: per-lane bf16 MFMA B-fragments, both layers in one kernel ---
// frag (ks, nt): lane l holds W[ks*32 + (l>>4)*8 + j][nt*16 + (l&15)], j=0..7,
// u32[p] = cvt_pk(w[2p], w[2p+1]) — identical (lane, elem)->k map as the A side.

static __device__ inline void wpack(const float* __restrict__ W, int kout, int idx,
                                    uint4* __restrict__ wfrag) {
  int nt_cnt = kout / 16;
  int lane = idx & 63;
  int nt = (idx >> 6) % nt_cnt;
  int ks = idx / (64 * nt_cnt);
  int g = lane >> 4, c = lane & 15;
  const float* wp = W + (ks * 32 + g * 8) * kout + nt * 16 + c;
  float w[8];
#pragma unroll
  for (int j = 0; j < 8; ++j) w[j] = wp[j * kout];
  wfrag[idx] = f32_to_bf8(w);
}

__global__ void k_wprep_all(const float* __restrict__ W1, const float* __restrict__ W2,
                            uint4* __restrict__ wf1, uint4* __restrict__ wf2) {
  int idx = blockIdx.x * 256 + threadIdx.x;
  if (idx < 2048) {
    wpack(W1, 128, idx, wf1);
  } else if (idx < 3072) {
    wpack(W2, 64, idx - 2048, wf2);
  }
}

// ---------------- MFMA GEMM 1: hs1[n,:] = bf16( dinv[n] * (x[n,:] @ W1) ) ----------
// One wave per 16-row stripe. No LDS, no barriers. f32 A-load + cvt_pk.

__global__ __launch_bounds__(256) void k_gemm1(const float* __restrict__ X,
                                               const uint4* __restrict__ wfrag,
                                               const float* __restrict__ dinv,
                                               unsigned short* __restrict__ Yb) {
  constexpr int NT = 8;  // 128 / 16
  const int tid = threadIdx.x;
  const int w = blockIdx.x * 4 + (tid >> 6);
  if (w >= ROWTILES) return;
  const int lane = tid & 63;
  const int g = lane >> 4, c = lane & 15;
  const int rb = w * 16;

  f32x4 acc[NT];
#pragma unroll
  for (int nt = 0; nt < NT; ++nt) acc[nt] = (f32x4){0.f, 0.f, 0.f, 0.f};

  const bf16x8* wf = (const bf16x8*)wfrag;
  const float* xrow = X + (long long)(rb + c) * 128 + g * 8;

#pragma unroll
  for (int ks = 0; ks < 4; ++ks) {
    float4 a0 = *(const float4*)(xrow + ks * 32);
    float4 a1 = *(const float4*)(xrow + ks * 32 + 4);
    union { bf16x8 v; uint32_t u[4]; } af;
    af.u[0] = cvt_pk_bf16(a0.x, a0.y);
    af.u[1] = cvt_pk_bf16(a0.z, a0.w);
    af.u[2] = cvt_pk_bf16(a1.x, a1.y);
    af.u[3] = cvt_pk_bf16(a1.z, a1.w);
#pragma unroll
    for (int nt = 0; nt < NT; ++nt) {
      bf16x8 bf = wf[(ks * NT + nt) * 64 + lane];
      acc[nt] = __builtin_amdgcn_mfma_f32_16x16x32_bf16(af.v, bf, acc[nt], 0, 0, 0);
    }
  }

  // C/D layout (m89-verified): col = lane&15, row = (lane>>4)*4 + reg
#pragma unroll
  for (int r = 0; r < 4; ++r) {
    int row = rb + g * 4 + r;
    float s = dinv[row];
#pragma unroll
    for (int nt = 0; nt < NT; ++nt) {
      float val = acc[nt][r] * s;
      Yb[(long long)row * 128 + nt * 16 + c] = (unsigned short)cvt_pk_bf16(val, val);
    }
  }
}

// ---------------- FUSED: layer-1 aggregation + layer-2 GEMM ----------------
// Wave owns 16 nodes. Lane l: node n = rb+(l&15), k-slice (l>>4)*8 of 128.
// agg row accumulated in regs (32 f32/lane = exactly the MFMA A-fragment layout),
// then bias+ReLU+cvt -> 4 MFMA k-steps vs wfrag2 -> hs2 (bf16). agg1 never hits memory.

__global__ __launch_bounds__(256) void k_gather_gemm2(
    const int* __restrict__ cursor, const int* __restrict__ deg,
    const int* __restrict__ csr_src, const float* __restrict__ dinv,
    const unsigned short* __restrict__ hs1, const float* __restrict__ b1,
    const uint4* __restrict__ wfrag2, unsigned short* __restrict__ hs2) {
  const int tid = threadIdx.x;
  const int w = blockIdx.x * 4 + (tid >> 6);
  if (w >= ROWTILES) return;
  const int lane = tid & 63;
  const int g = lane >> 4, c = lane & 15;
  const int rb = w * 16;
  const int n = rb + c;
  const float d = dinv[n];
  const int end = cursor[n];
  const int dg = deg[n];

  float acc[4][8];
  {  // self term
    const unsigned short* hrow = hs1 + (long long)n * 128 + g * 8;
#pragma unroll
    for (int ks = 0; ks < 4; ++ks) bf8_to_f32(*(const uint4*)(hrow + ks * 32), acc[ks]);
  }

  int s = end - dg;
  for (; s + 2 <= end; s += 2) {
    int s0 = csr_src[s], s1 = csr_src[s + 1];
    const unsigned short* p0 = hs1 + (long long)s0 * 128 + g * 8;
    const unsigned short* p1 = hs1 + (long long)s1 * 128 + g * 8;
#pragma unroll
    for (int ks = 0; ks < 4; ++ks) {
      float v0[8], v1[8];
      bf8_to_f32(*(const uint4*)(p0 + ks * 32), v0);
      bf8_to_f32(*(const uint4*)(p1 + ks * 32), v1);
#pragma unroll
      for (int j = 0; j < 8; ++j) acc[ks][j] += v0[j] + v1[j];
    }
  }
  if (s < end) {
    const unsigned short* p0 = hs1 + (long long)csr_src[s] * 128 + g * 8;
#pragma unroll
    for (int ks = 0; ks < 4; ++ks) {
      float v0[8];
      bf8_to_f32(*(const uint4*)(p0 + ks * 32), v0);
#pragma unroll
      for (int j = 0; j < 8; ++j) acc[ks][j] += v0[j];
    }
  }

  // agg1 row slice = relu(b1 + d*acc) -> bf16 A-fragments
  union { bf16x8 v; uint32_t u[4]; } av[4];
#pragma unroll
  for (int ks = 0; ks < 4; ++ks) {
    float4 bv0 = *(const float4*)&b1[ks * 32 + g * 8];
    float4 bv1 = *(const float4*)&b1[ks * 32 + g * 8 + 4];
    float r8[8];
    r8[0] = fmaxf(bv0.x + d * acc[ks][0], 0.f);
    r8[1] = fmaxf(bv0.y + d * acc[ks][1], 0.f);
    r8[2] = fmaxf(bv0.z + d * acc[ks][2], 0.f);
    r8[3] = fmaxf(bv0.w + d * acc[ks][3], 0.f);
    r8[4] = fmaxf(bv1.x + d * acc[ks][4], 0.f);
    r8[5] = fmaxf(bv1.y + d * acc[ks][5], 0.f);
    r8[6] = fmaxf(bv1.z + d * acc[ks][6], 0.f);
    r8[7] = fmaxf(bv1.w + d * acc[ks][7], 0.f);
    av[ks].u[0] = cvt_pk_bf16(r8[0], r8[1]);
    av[ks].u[1] = cvt_pk_bf16(r8[2], r8[3]);
    av[ks].u[2] = cvt_pk_bf16(r8[4], r8[5]);
    av[ks].u[3] = cvt_pk_bf16(r8[6], r8[7]);
  }

  // layer-2 MFMA: hs2 stripe = dinv * (agg1 @ W2)
  f32x4 accm[4];
#pragma unroll
  for (int nt = 0; nt < 4; ++nt) accm[nt] = (f32x4){0.f, 0.f, 0.f, 0.f};
  const bf16x8* wf = (const bf16x8*)wfrag2;
#pragma unroll
  for (int ks = 0; ks < 4; ++ks) {
#pragma unroll
    for (int nt = 0; nt < 4; ++nt) {
      bf16x8 bf = wf[(ks * 4 + nt) * 64 + lane];
      accm[nt] = __builtin_amdgcn_mfma_f32_16x16x32_bf16(av[ks].v, bf, accm[nt], 0, 0, 0);
    }
  }

#pragma unroll
  for (int r = 0; r < 4; ++r) {
    int row = rb + g * 4 + r;
    float sc = dinv[row];
#pragma unroll
    for (int nt = 0; nt < 4; ++nt) {
      float val = accm[nt][r] * sc;
      hs2[(long long)row * 64 + nt * 16 + c] = (unsigned short)cvt_pk_bf16(val, val);
    }
  }
}

// ---- final gather: out[n] = b2 + dinv[n]*(hs2[n] + sum_src hs2[src]), f32 out ----

__global__ __launch_bounds__(256) void k_gather_out(
    const int* __restrict__ cursor, const int* __restrict__ deg,
    const int* __restrict__ csr_src, const float* __restrict__ dinv,
    const unsigned short* __restrict__ hs, const float* __restrict__ bias,
    float* __restrict__ out) {
  constexpr int C = 64, Q = 8;
  int idx = blockIdx.x * 256 + threadIdx.x;
  if (idx >= N_NODES * Q) return;
  int n = idx / Q, q = idx % Q;
  float d = dinv[n];
  int end = cursor[n];
  int dg = deg[n];

  float acc[8];
  bf8_to_f32(*(const uint4*)&hs[(long long)n * C + q * 8], acc);  // self term

  int s = end - dg;
  for (; s + 2 <= end; s += 2) {
    int s0 = csr_src[s], s1 = csr_src[s + 1];
    uint4 u0 = *(const uint4*)&hs[(long long)s0 * C + q * 8];
    uint4 u1 = *(const uint4*)&hs[(long long)s1 * C + q * 8];
    float v0[8], v1[8];
    bf8_to_f32(u0, v0);
    bf8_to_f32(u1, v1);
#pragma unroll
    for (int j = 0; j < 8; ++j) acc[j] += v0[j] + v1[j];
  }
  if (s < end) {
    float v0[8];
    bf8_to_f32(*(const uint4*)&hs[(long long)csr_src[s] * C + q * 8], v0);
#pragma unroll
    for (int j = 0; j < 8; ++j) acc[j] += v0[j];
  }

  float4 bv0 = *(const float4*)&bias[q * 8];
  float4 bv1 = *(const float4*)&bias[q * 8 + 4];
  float4 o0 = {bv0.x + d * acc[0], bv0.y + d * acc[1], bv0.z + d * acc[2],
               bv0.w + d * acc[3]};
  float4 o1 = {bv1.x + d * acc[4], bv1.y + d * acc[5], bv1.z + d * acc[6],
               bv1.w + d * acc[7]};
  *(float4*)&out[(long long)n * C + q * 8] = o0;
  *(float4*)&out[(long long)n * C + q * 8 + 4] = o1;
}

// ---------------- launch ----------------

extern "C" void kernel_launch(void* const* d_in, const int* in_sizes, int n_in,
                              void* d_out, int out_size, void* d_ws, size_t ws_size,
                              hipStream_t stream) {
  const float* x = (const float*)d_in[0];
  const int* ei = (const int*)d_in[1];
  const int* erow = ei;            // sources
  const int* ecol = ei + N_EDGES;  // targets
  const float* W1 = (const float*)d_in[2];
  const float* b1 = (const float*)d_in[3];
  const float* W2 = (const float*)d_in[4];
  const float* b2 = (const float*)d_in[5];
  float* out = (float*)d_out;

  char* ws = (char*)d_ws;
  int* deg = (int*)(ws + 0);                     // 400,000 B
  int* cursor = (int*)(ws + 400128);             // 400,000 B
  int* excl = (int*)(ws + 800256);               // 400,000 B
  int* bsum = (int*)(ws + 1200384);              // 512 B
  int* csr_src = (int*)(ws + 1200896);           // 2,560,000 B
  float* dinv = (float*)(ws + 3760896);          // 400,000 B
  unsigned short* hs1 = (unsigned short*)(ws + 4161024);  // 25.6 MB (bf16)
  unsigned short* hs2 = (unsigned short*)(ws + 29761024); // 12.8 MB (bf16)
  uint4* wfrag1 = (uint4*)(ws + 42561024);       // 32 KB
  uint4* wfrag2 = (uint4*)(ws + 42593792);       // 16 KB

  // deg = 0 (memsetAsync is graph-capturable); W fragment packing (1 kernel)
  hipMemsetAsync(deg, 0, N_NODES * sizeof(int), stream);
  k_wprep_all<<<12, 256, 0, stream>>>(W1, W2, wfrag1, wfrag2);

  // CSR build
  k_hist<<<(N_EDGES + 255) / 256, 256, 0, stream>>>(ecol, deg);
  k_scan1<<<NSCANB, 256, 0, stream>>>(deg, excl, bsum);
  k_scan2<<<1, 128, 0, stream>>>(bsum);
  k_scan3<<<(N_NODES + 255) / 256, 256, 0, stream>>>(excl, bsum, deg, cursor, dinv);
  k_fill<<<(N_EDGES + 255) / 256, 256, 0, stream>>>(erow, ecol, cursor, csr_src);

  const int gblocks = (ROWTILES + 3) / 4;  // 1563

  // layer 1 GEMM -> hs1 (bf16)
  k_gemm1<<<gblocks, 256, 0, stream>>>(x, wfrag1, dinv, hs1);
  // fused layer-1 aggregation + layer-2 GEMM -> hs2 (bf16); agg1 never materialized
  k_gather_gemm2<<<gblocks, 256, 0, stream>>>(cursor, deg, csr_src, dinv, hs1, b1,
                                              wfrag2, hs2);
  // final aggregation -> out (f32)
  k_gather_out<<<N_NODES * 8 / 256, 256, 0, stream>>>(cursor, deg, csr_src, dinv, hs2,
                                                      b2, out);
}